// Round 6
// baseline (73.254 us; speedup 1.0000x reference)
//
#include <hip/hip_runtime.h>

typedef float f32x2 __attribute__((ext_vector_type(2)));
typedef float f32x16 __attribute__((ext_vector_type(16)));
typedef __bf16 bf16x8 __attribute__((ext_vector_type(8)));

static __device__ __forceinline__ unsigned short f2bf(float v) {
    unsigned u = __builtin_bit_cast(unsigned, v);
    unsigned r = (u + 0x7FFFu + ((u >> 16) & 1u)) >> 16;
    return (unsigned short)r;
}
static __device__ __forceinline__ float bf2f(unsigned short h) {
    unsigned u = ((unsigned)h) << 16;
    return __builtin_bit_cast(float, u);
}
static __device__ __forceinline__ bf16x8 ldg8(const unsigned short* p) {
    uint4 u = *(const uint4*)p;
    return __builtin_bit_cast(bf16x8, u);
}
static __device__ __forceinline__ f32x16 mfma32(bf16x8 a, bf16x8 b, f32x16 c) {
    return __builtin_amdgcn_mfma_f32_32x32x16_bf16(a, b, c, 0, 0, 0);
}

// ---------------------------------------------------------------------------
// prep_M: simulate the 64 basis states for each f -> M_f (64x64 complex),
// bf16 hi/lo, layout [f][re/im][d][k]. (verified R1-R5)
// ---------------------------------------------------------------------------
__global__ __launch_bounds__(256) void prep_M(const float* __restrict__ wts,
                                              unsigned short* __restrict__ Mhi,
                                              unsigned short* __restrict__ Mlo) {
    __shared__ float gls[12][8];
    const int f = blockIdx.x >> 4;
    const int tid = threadIdx.x;
    if (tid < 12) {
        int l = tid / 6, w = tid % 6;
        const float* p = wts + ((f * 2 + l) * 6 + w) * 3;
        float phi = p[0], theta = p[1], omega = p[2];
        float c, s; sincosf(0.5f * theta, &s, &c);
        float sapo, capo, samo, camo;
        sincosf(0.5f * (phi + omega), &sapo, &capo);
        sincosf(0.5f * (phi - omega), &samo, &camo);
        float* o = gls[tid];
        o[0] =  capo * c;  o[1] = -sapo * c;
        o[2] = -camo * s;  o[3] = -samo * s;
        o[4] =  camo * s;  o[5] = -samo * s;
        o[6] =  capo * c;  o[7] =  sapo * c;
    }
    __syncthreads();

    const int lane = tid & 63;
    const int wid  = tid >> 6;
    const int bas  = (blockIdx.x & 15) * 4 + wid;

    int src0 = lane, src1 = lane;
#pragma unroll
    for (int w = 5; w >= 0; --w) { int tq = (w + 1) % 6; src0 ^= ((src0 >> (5 - w)) & 1) << (5 - tq); }
#pragma unroll
    for (int w = 5; w >= 0; --w) { int tq = (w + 2) % 6; src1 ^= ((src1 >> (5 - w)) & 1) << (5 - tq); }

    float ar = (lane == bas) ? 1.0f : 0.0f, ai = 0.0f;
#pragma unroll
    for (int rep = 0; rep < 2; ++rep) {
#pragma unroll
        for (int l = 0; l < 2; ++l) {
#pragma unroll
            for (int w = 0; w < 6; ++w) {
                const float* gp = gls[l * 6 + w];
                const float4 uA = *(const float4*)gp;
                const float4 uB = *(const float4*)(gp + 4);
                const int m = 32 >> w;
                const float br = __shfl_xor(ar, m);
                const float bi = __shfl_xor(ai, m);
                const bool hi = (lane & m) != 0;
                const float cmr = hi ? uB.z : uA.x;
                const float cmi = hi ? uB.w : uA.y;
                const float cpr = hi ? uB.x : uA.z;
                const float cpi = hi ? uB.y : uA.w;
                const float nr = cmr * ar - cmi * ai + cpr * br - cpi * bi;
                const float ni = cmr * ai + cmi * ar + cpr * bi + cpi * br;
                ar = nr; ai = ni;
            }
            const int src = l ? src1 : src0;
            ar = __shfl(ar, src);
            ai = __shfl(ai, src);
        }
    }
    const int o_re = ((f * 2 + 0) * 64 + lane) * 64 + bas;
    const int o_im = ((f * 2 + 1) * 64 + lane) * 64 + bas;
    unsigned short hr = f2bf(ar);
    Mhi[o_re] = hr; Mlo[o_re] = f2bf(ar - bf2f(hr));
    unsigned short hm = f2bf(ai);
    Mhi[o_im] = hm; Mlo[o_im] = f2bf(ai - bf2f(hm));
}

// ---------------------------------------------------------------------------
// Main: 32 patches/block (3844 blocks), 4 waves <-> d-quarters, one 32-col
// tile. Single sync before one combine pass. LDS union 12 KB.
// ---------------------------------------------------------------------------
__global__ __launch_bounds__(256, 4) void qconv_main(
        const float* __restrict__ x,
        const unsigned short* __restrict__ Mhi,
        const unsigned short* __restrict__ Mlo,
        float* __restrict__ out) {
    __shared__ __align__(16) unsigned char smem[12288];
    unsigned short* psiH = (unsigned short*)smem;            // 4 KB (32x64)
    unsigned short* psiL = (unsigned short*)(smem + 4096);   // 4 KB
    float* zbuf = (float*)smem;                              // 12 KB, reused

    const int tid  = threadIdx.x;
    const int lane = tid & 63;
    const int w    = tid >> 6;
    const int n0   = blockIdx.x * 32;

    // ---- front-end: 8 threads/patch, 8 elems each ----
    {
        const int p = tid >> 3;          // patch 0..31
        const int s = tid & 7;           // k-chunk of 8: k = s*8 .. s*8+7
        const int n = n0 + p;
        const int b = n / 961, pos = n - b * 961;
        const int i = pos / 31, j = pos - i * 31;
        const int c   = s >> 1;
        const int kh0 = (s & 1) * 2;
        const float* r0 = x + (((b * 4 + c) * 64) + (i * 2 + kh0)) * 64 + j * 2;
        const float* r1 = r0 + 64;
        float v[8];
        *(f32x2*)&v[0] = *(const f32x2*)r0;
        *(f32x2*)&v[2] = *(const f32x2*)(r0 + 2);
        *(f32x2*)&v[4] = *(const f32x2*)r1;
        *(f32x2*)&v[6] = *(const f32x2*)(r1 + 2);
        float ss = 0.f;
#pragma unroll
        for (int k = 0; k < 8; ++k) ss += v[k] * v[k];
        ss += __shfl_xor(ss, 1);
        ss += __shfl_xor(ss, 2);
        ss += __shfl_xor(ss, 4);
        const float rn = rsqrtf(ss);
        unsigned hu[4], lu[4];
#pragma unroll
        for (int k2 = 0; k2 < 4; ++k2) {
            float s0 = v[2 * k2] * rn, s1 = v[2 * k2 + 1] * rn;
            __bf16 h0 = (__bf16)s0, h1 = (__bf16)s1;
            __bf16 l0 = (__bf16)(s0 - (float)h0), l1 = (__bf16)(s1 - (float)h1);
            hu[k2] = (unsigned)__builtin_bit_cast(unsigned short, h0)
                   | ((unsigned)__builtin_bit_cast(unsigned short, h1) << 16);
            lu[k2] = (unsigned)__builtin_bit_cast(unsigned short, l0)
                   | ((unsigned)__builtin_bit_cast(unsigned short, l1) << 16);
        }
        const int idx = p * 64 + (s ^ (p & 7)) * 8;
        *(uint4*)&psiH[idx] = make_uint4(hu[0], hu[1], hu[2], hu[3]);
        *(uint4*)&psiL[idx] = make_uint4(lu[0], lu[1], lu[2], lu[3]);
    }
    __syncthreads();

    // ---- B-fragments into registers ----
    bf16x8 Bh[4], Bl[4];
    const int pc  = lane & 31;
    const int hi5 = lane >> 5;
#pragma unroll
    for (int ks = 0; ks < 4; ++ks) {
        const int idx = pc * 64 + ((2 * ks + hi5) ^ (pc & 7)) * 8;
        Bh[ks] = __builtin_bit_cast(bf16x8, *(const uint4*)&psiH[idx]);
        Bl[ks] = __builtin_bit_cast(bf16x8, *(const uint4*)&psiL[idx]);
    }
    __syncthreads();   // psi LDS dead; reuse as zbuf

    // A-row base: reim from lane bit4, d = w*16 + (lane&15), k-half lane bit5
    const int arow = ((lane >> 4) & 1) * 4096 + (w * 16 + (lane & 15)) * 64 + hi5 * 8;

#pragma unroll 1
    for (int f = 0; f < 4; ++f) {
        const int off = f * 8192 + arow;
        bf16x8 Ah[4], Al[4];
#pragma unroll
        for (int ks = 0; ks < 4; ++ks) {
            Ah[ks] = ldg8(Mhi + off + ks * 16);
            Al[ks] = ldg8(Mlo + off + ks * 16);
        }
        f32x16 C;
#pragma unroll
        for (int r = 0; r < 16; ++r) C[r] = 0.f;
#pragma unroll
        for (int ks = 0; ks < 4; ++ks) {
            C = mfma32(Ah[ks], Bh[ks], C);
            C = mfma32(Ah[ks], Bl[ks], C);
            C = mfma32(Al[ks], Bh[ks], C);
        }
        // epilogue: P lane-local (re=regs 0-7, im=regs 8-15, same d)
        float P[8];
#pragma unroll
        for (int r = 0; r < 8; ++r) P[r] = C[r] * C[r] + C[r + 8] * C[r + 8];
        const float e0 = P[0] + P[1], o0 = P[0] - P[1];
        const float e1 = P[2] + P[3], o1 = P[2] - P[3];
        const float e2 = P[4] + P[5], o2 = P[4] - P[5];
        const float e3 = P[6] + P[7], o3 = P[6] - P[7];
        const float s01 = e0 + e1, s23 = e2 + e3;
        float S  = s01 + s23;
        float Z2 = s01 - s23;                 // sign by d&8 (r>>2)
        float Z4 = (e0 - e1) + (e2 - e3);     // sign by d&2 (r&2)
        float Z5 = o0 + o1 + o2 + o3;         // sign by d&1 (r&1)
        float Z3 = hi5 ? -S : S;              // sign by d&4 (hi5)
        S  += __shfl_xor(S, 32);
        Z2 += __shfl_xor(Z2, 32);
        Z3 += __shfl_xor(Z3, 32);
        Z4 += __shfl_xor(Z4, 32);
        Z5 += __shfl_xor(Z5, 32);
        if (lane < 32) {
            float* zb = zbuf + (f * 6 * 4 + w) * 32 + lane;
            zb[0 * 128] = (w & 2) ? -S : S;   // q0: d bit5 = w>>1
            zb[1 * 128] = (w & 1) ? -S : S;   // q1: d bit4 = w&1
            zb[2 * 128] = Z2;
            zb[3 * 128] = Z3;
            zb[4 * 128] = Z4;
            zb[5 * 128] = Z5;
        }
    }
    __syncthreads();

    // ---- combine across waves + store ----
#pragma unroll 1
    for (int u = tid; u < 768; u += 256) {
        const int f   = u / 192;
        const int rem = u - f * 192;
        const int q   = rem >> 5;
        const int p   = rem & 31;
        const float* zb = zbuf + (f * 6 + q) * 128 + p;
        const float sum = zb[0] + zb[32] + zb[64] + zb[96];
        const int n = n0 + p;
        const int b = n / 961, pos = n - b * 961;
        out[(b * 24 + f * 6 + q) * 961 + pos] = sum;
    }
}

extern "C" void kernel_launch(void* const* d_in, const int* in_sizes, int n_in,
                              void* d_out, int out_size, void* d_ws, size_t ws_size,
                              hipStream_t stream) {
    const float* x   = (const float*)d_in[0];   // (128, 4, 64, 64)
    const float* wts = (const float*)d_in[1];   // (4, 2, 6, 3)
    float* out = (float*)d_out;                 // (128, 24, 31, 31)

    unsigned short* Mhi = (unsigned short*)d_ws;
    unsigned short* Mlo = (unsigned short*)((char*)d_ws + 65536);

    prep_M<<<64, 256, 0, stream>>>(wts, Mhi, Mlo);

    const int npatch = 128 * 31 * 31;           // 123008 = 3844 * 32
    qconv_main<<<npatch / 32, 256, 0, stream>>>(x, Mhi, Mlo, out);
}

// Round 7
// 32.107 us; speedup vs baseline: 2.2816x; 2.2816x over previous
//
#include <hip/hip_runtime.h>

typedef float f32x2 __attribute__((ext_vector_type(2)));
typedef float f32x16 __attribute__((ext_vector_type(16)));
typedef __bf16 bf16x8 __attribute__((ext_vector_type(8)));

static __device__ __forceinline__ unsigned short f2bf(float v) {
    unsigned u = __builtin_bit_cast(unsigned, v);
    unsigned r = (u + 0x7FFFu + ((u >> 16) & 1u)) >> 16;
    return (unsigned short)r;
}
static __device__ __forceinline__ float bf2f(unsigned short h) {
    unsigned u = ((unsigned)h) << 16;
    return __builtin_bit_cast(float, u);
}
static __device__ __forceinline__ bf16x8 ldg8(const unsigned short* p) {
    uint4 u = *(const uint4*)p;
    return __builtin_bit_cast(bf16x8, u);
}
static __device__ __forceinline__ f32x16 mfma32(bf16x8 a, bf16x8 b, f32x16 c) {
    return __builtin_amdgcn_mfma_f32_32x32x16_bf16(a, b, c, 0, 0, 0);
}

// ---------------------------------------------------------------------------
// prep_M: simulate the 64 basis states for each f -> M_f (64x64 complex),
// bf16 hi, layout [f][re/im][d][k]. (simulation verified R1-R6)
// ---------------------------------------------------------------------------
__global__ __launch_bounds__(256) void prep_M(const float* __restrict__ wts,
                                              unsigned short* __restrict__ Mhi) {
    __shared__ float gls[12][8];
    const int f = blockIdx.x >> 4;
    const int tid = threadIdx.x;
    if (tid < 12) {
        int l = tid / 6, w = tid % 6;
        const float* p = wts + ((f * 2 + l) * 6 + w) * 3;
        float phi = p[0], theta = p[1], omega = p[2];
        float c, s; sincosf(0.5f * theta, &s, &c);
        float sapo, capo, samo, camo;
        sincosf(0.5f * (phi + omega), &sapo, &capo);
        sincosf(0.5f * (phi - omega), &samo, &camo);
        float* o = gls[tid];
        o[0] =  capo * c;  o[1] = -sapo * c;
        o[2] = -camo * s;  o[3] = -samo * s;
        o[4] =  camo * s;  o[5] = -samo * s;
        o[6] =  capo * c;  o[7] =  sapo * c;
    }
    __syncthreads();

    const int lane = tid & 63;
    const int wid  = tid >> 6;
    const int bas  = (blockIdx.x & 15) * 4 + wid;

    int src0 = lane, src1 = lane;
#pragma unroll
    for (int w = 5; w >= 0; --w) { int tq = (w + 1) % 6; src0 ^= ((src0 >> (5 - w)) & 1) << (5 - tq); }
#pragma unroll
    for (int w = 5; w >= 0; --w) { int tq = (w + 2) % 6; src1 ^= ((src1 >> (5 - w)) & 1) << (5 - tq); }

    float ar = (lane == bas) ? 1.0f : 0.0f, ai = 0.0f;
#pragma unroll
    for (int rep = 0; rep < 2; ++rep) {
#pragma unroll
        for (int l = 0; l < 2; ++l) {
#pragma unroll
            for (int w = 0; w < 6; ++w) {
                const float* gp = gls[l * 6 + w];
                const float4 uA = *(const float4*)gp;
                const float4 uB = *(const float4*)(gp + 4);
                const int m = 32 >> w;
                const float br = __shfl_xor(ar, m);
                const float bi = __shfl_xor(ai, m);
                const bool hi = (lane & m) != 0;
                const float cmr = hi ? uB.z : uA.x;
                const float cmi = hi ? uB.w : uA.y;
                const float cpr = hi ? uB.x : uA.z;
                const float cpi = hi ? uB.y : uA.w;
                const float nr = cmr * ar - cmi * ai + cpr * br - cpi * bi;
                const float ni = cmr * ai + cmi * ar + cpr * bi + cpi * br;
                ar = nr; ai = ni;
            }
            const int src = l ? src1 : src0;
            ar = __shfl(ar, src);
            ai = __shfl(ai, src);
        }
    }
    Mhi[((f * 2 + 0) * 64 + lane) * 64 + bas] = f2bf(ar);
    Mhi[((f * 2 + 1) * 64 + lane) * 64 + bas] = f2bf(ai);
}

// ---------------------------------------------------------------------------
// Main: 64 patches/block, 4 waves <-> d-quarters, 32x32x16 MFMA, pure bf16.
// A-loads hoisted per f-pair; LDS union psi/zbuf 12 KB.
// ---------------------------------------------------------------------------
__global__ __launch_bounds__(256, 4) void qconv_main(
        const float* __restrict__ x,
        const unsigned short* __restrict__ Mhi,
        float* __restrict__ out) {
    __shared__ __align__(16) unsigned char smem[12288];
    unsigned short* psiH = (unsigned short*)smem;   // 8 KB (64x64 bf16)
    float* zbuf = (float*)smem;                     // 12 KB, reused

    const int tid  = threadIdx.x;
    const int lane = tid & 63;
    const int w    = tid >> 6;
    const int n0   = blockIdx.x * 64;

    // ---- front-end: load, norm, bf16, stage psi ----
    {
        const int p = tid >> 2;          // patch 0..63
        const int q = tid & 3;           // channel / k-chunk
        const int n = n0 + p;
        const int b = n / 961, pos = n - b * 961;
        const int i = pos / 31, j = pos - i * 31;
        const float* base = x + (((b * 4 + q) * 64) + i * 2) * 64 + j * 2;
        float v[16];
#pragma unroll
        for (int kh = 0; kh < 4; ++kh) {
            const float* r = base + kh * 64;
            *(f32x2*)&v[kh * 4]     = *(const f32x2*)r;
            *(f32x2*)&v[kh * 4 + 2] = *(const f32x2*)(r + 2);
        }
        float ss = 0.f;
#pragma unroll
        for (int k = 0; k < 16; ++k) ss += v[k] * v[k];
        ss += __shfl_xor(ss, 1);
        ss += __shfl_xor(ss, 2);
        const float rn = rsqrtf(ss);
        unsigned hu[8];
#pragma unroll
        for (int k2 = 0; k2 < 8; ++k2) {
            __bf16 h0 = (__bf16)(v[2 * k2] * rn);
            __bf16 h1 = (__bf16)(v[2 * k2 + 1] * rn);
            hu[k2] = (unsigned)__builtin_bit_cast(unsigned short, h0)
                   | ((unsigned)__builtin_bit_cast(unsigned short, h1) << 16);
        }
        const int s0i = p * 64 + ((2 * q) ^ (p & 7)) * 8;
        const int s1i = p * 64 + ((2 * q + 1) ^ (p & 7)) * 8;
        *(uint4*)&psiH[s0i] = make_uint4(hu[0], hu[1], hu[2], hu[3]);
        *(uint4*)&psiH[s1i] = make_uint4(hu[4], hu[5], hu[6], hu[7]);
    }
    __syncthreads();

    // ---- B-fragments into registers (kept for whole kernel) ----
    bf16x8 Bh[2][4];
    {
        const int pc = lane & 31, hi = lane >> 5;
#pragma unroll
        for (int ct = 0; ct < 2; ++ct) {
            const int pp = ct * 32 + pc;
#pragma unroll
            for (int ks = 0; ks < 4; ++ks) {
                const int idx = pp * 64 + ((2 * ks + hi) ^ (pp & 7)) * 8;
                Bh[ct][ks] = __builtin_bit_cast(bf16x8, *(const uint4*)&psiH[idx]);
            }
        }
    }
    __syncthreads();   // psi LDS dead; reuse as zbuf

    // A-row base: reim from lane bit4, d = w*16 + (lane&15), k-half lane bit5
    const int arow = ((lane >> 4) & 1) * 4096 + (w * 16 + (lane & 15)) * 64 + (lane >> 5) * 8;
    const int hi5 = lane >> 5;

#pragma unroll 1
    for (int fp = 0; fp < 2; ++fp) {
        // hoist both f's A-fragments: 8 ldg8, one latency exposure per pair
        bf16x8 A8[2][4];
#pragma unroll
        for (int fo = 0; fo < 2; ++fo) {
            const int off = (fp * 2 + fo) * 8192 + arow;
#pragma unroll
            for (int ks = 0; ks < 4; ++ks) A8[fo][ks] = ldg8(Mhi + off + ks * 16);
        }
#pragma unroll
        for (int fo = 0; fo < 2; ++fo) {
            f32x16 C0, C1;
#pragma unroll
            for (int r = 0; r < 16; ++r) { C0[r] = 0.f; C1[r] = 0.f; }
#pragma unroll
            for (int ks = 0; ks < 4; ++ks) {
                C0 = mfma32(A8[fo][ks], Bh[0][ks], C0);
                C1 = mfma32(A8[fo][ks], Bh[1][ks], C1);
            }
            // epilogue: P lane-local (re=regs 0-7, im=regs 8-15, same d)
#pragma unroll
            for (int ct = 0; ct < 2; ++ct) {
                const f32x16 Cv = ct ? C1 : C0;
                float P[8];
#pragma unroll
                for (int r = 0; r < 8; ++r) P[r] = Cv[r] * Cv[r] + Cv[r + 8] * Cv[r + 8];
                const float e0 = P[0] + P[1], o0 = P[0] - P[1];
                const float e1 = P[2] + P[3], o1 = P[2] - P[3];
                const float e2 = P[4] + P[5], o2 = P[4] - P[5];
                const float e3 = P[6] + P[7], o3 = P[6] - P[7];
                const float s01 = e0 + e1, s23 = e2 + e3;
                float S  = s01 + s23;
                float Z2 = s01 - s23;                 // sign by d&8 (r>>2)
                float Z4 = (e0 - e1) + (e2 - e3);     // sign by d&2 (r&2)
                float Z5 = o0 + o1 + o2 + o3;         // sign by d&1 (r&1)
                float Z3 = hi5 ? -S : S;              // sign by d&4 (hi5)
                S  += __shfl_xor(S, 32);
                Z2 += __shfl_xor(Z2, 32);
                Z3 += __shfl_xor(Z3, 32);
                Z4 += __shfl_xor(Z4, 32);
                Z5 += __shfl_xor(Z5, 32);
                if (lane < 32) {
                    const int pp = ct * 32 + lane;
                    zbuf[((fo * 6 + 0) * 4 + w) * 64 + pp] = (w & 2) ? -S : S;
                    zbuf[((fo * 6 + 1) * 4 + w) * 64 + pp] = (w & 1) ? -S : S;
                    zbuf[((fo * 6 + 2) * 4 + w) * 64 + pp] = Z2;
                    zbuf[((fo * 6 + 3) * 4 + w) * 64 + pp] = Z3;
                    zbuf[((fo * 6 + 4) * 4 + w) * 64 + pp] = Z4;
                    zbuf[((fo * 6 + 5) * 4 + w) * 64 + pp] = Z5;
                }
            }
        }
        __syncthreads();
        // ---- combine across waves + store (2 f's worth) ----
#pragma unroll 1
        for (int u = tid; u < 768; u += 256) {
            const int fo  = u / 384;
            const int rem = u - fo * 384;
            const int q   = rem >> 6;
            const int p   = rem & 63;
            const int zb  = (fo * 6 + q) * 4 * 64 + p;
            const float sum = zbuf[zb] + zbuf[zb + 64] + zbuf[zb + 128] + zbuf[zb + 192];
            const int f = fp * 2 + fo;
            const int n = n0 + p;
            const int b = n / 961, pos = n - b * 961;
            out[(b * 24 + f * 6 + q) * 961 + pos] = sum;
        }
        __syncthreads();
    }
}

extern "C" void kernel_launch(void* const* d_in, const int* in_sizes, int n_in,
                              void* d_out, int out_size, void* d_ws, size_t ws_size,
                              hipStream_t stream) {
    const float* x   = (const float*)d_in[0];   // (128, 4, 64, 64)
    const float* wts = (const float*)d_in[1];   // (4, 2, 6, 3)
    float* out = (float*)d_out;                 // (128, 24, 31, 31)

    unsigned short* Mhi = (unsigned short*)d_ws;

    prep_M<<<64, 256, 0, stream>>>(wts, Mhi);

    const int npatch = 128 * 31 * 31;           // 123008 = 1922 * 64
    qconv_main<<<npatch / 64, 256, 0, stream>>>(x, Mhi, out);
}